// Round 13
// baseline (1158.297 us; speedup 1.0000x reference)
//
#include <hip/hip_runtime.h>
#include <math.h>

#define V_N 8192
#define D_F 128
#define E_N 262144
#define K_N 512
#define DMAXF 0.5f
#define EPSW 1e-8f
#define EPSL 1e-5f
#define MAX_SE 16384
#define NZ_SYRK 24
#define L68 68

#define NB_TR 1024
#define NB_CP 256
#define NB_ED (E_N / 64)

// ---------- fused pre-pass: transpose pmat (KxV)->PT (VxK) | Lw1 <- T | edge dedup ----------
__global__ __launch_bounds__(256) void k_pre(const float* __restrict__ P, float* __restrict__ PT,
                                             const float* __restrict__ X, const int* __restrict__ ei,
                                             int* __restrict__ cnt, int* __restrict__ si,
                                             int* __restrict__ sj, float* __restrict__ sw,
                                             unsigned* __restrict__ htab,
                                             const float* __restrict__ T, float* __restrict__ Lw1) {
  int b = blockIdx.x, tid = threadIdx.x;
  if (b < NB_TR) {
    __shared__ float tl[64][65];
    int v0 = (b & 127) * 64, k0 = (b >> 7) * 64;
    int c4 = tid & 15, rq = tid >> 4;
#pragma unroll
    for (int rr = 0; rr < 4; ++rr) {
      int r = rq + 16 * rr;
      float4 f = *(const float4*)&P[(size_t)(k0 + r) * V_N + v0 + c4 * 4];
      tl[r][c4 * 4 + 0] = f.x; tl[r][c4 * 4 + 1] = f.y;
      tl[r][c4 * 4 + 2] = f.z; tl[r][c4 * 4 + 3] = f.w;
    }
    __syncthreads();
#pragma unroll
    for (int rr = 0; rr < 4; ++rr) {
      int r = rq + 16 * rr;   // v-local row
      float4 f;
      f.x = tl[c4 * 4 + 0][r]; f.y = tl[c4 * 4 + 1][r];
      f.z = tl[c4 * 4 + 2][r]; f.w = tl[c4 * 4 + 3][r];
      *(float4*)&PT[(size_t)(v0 + r) * K_N + k0 + c4 * 4] = f;
    }
  } else if (b < NB_TR + NB_CP) {
    int idx = (b - NB_TR) * 256 + tid;
    ((float4*)Lw1)[idx] = ((const float4*)T)[idx];
  } else {
    // per-edge distance (4 lanes/edge -> 16 independent float4 loads in flight per lane)
    int t = (b - NB_TR - NB_CP) * 256 + tid;
    int e = t >> 2, lane = t & 3;
    int i = ei[e], j = ei[E_N + e];
    const float4* xi = (const float4*)(X + (size_t)i * D_F);
    const float4* xj = (const float4*)(X + (size_t)j * D_F);
    float d = 0.f;
#pragma unroll
    for (int q = 0; q < 8; ++q) {
      float4 a = xi[lane * 8 + q];
      float4 bb = xj[lane * 8 + q];
      float dx;
      dx = a.x - bb.x; d += dx * dx;
      dx = a.y - bb.y; d += dx * dx;
      dx = a.z - bb.z; d += dx * dx;
      dx = a.w - bb.w; d += dx * dx;
    }
    d += __shfl_xor(d, 1);
    d += __shfl_xor(d, 2);
    if (lane == 0 && d <= DMAXF) {
      float w = expf(-d);
      unsigned a = (unsigned)min(i, j), bb = (unsigned)max(i, j);
      unsigned key = a * 8192u + bb;         // key==0 impossible (a<b)
      unsigned h = (key * 2654435761u) >> 16;
      bool isnew = false;
      for (int probe = 0; probe < 65536; ++probe) {
        unsigned slot = (h + (unsigned)probe) & 65535u;
        unsigned prev = atomicCAS(&htab[slot], 0u, key);
        if (prev == 0u) { isnew = true; break; }
        if (prev == key) break;              // duplicate pair -> reference counts it once
      }
      if (isnew) {
        int p = atomicAdd(cnt, 1);
        if (p < MAX_SE) { si[p] = i; sj[p] = j; sw[p] = w; }
      }
    }
  }
}

// ---------- La(lower) += Q^T Q + eps*I, Q rows = sqrt(w)*(PT[i]-PT[j]); fused trace epilogue ----------
__global__ __launch_bounds__(256) void k_syrk(const int* __restrict__ cnt, const int* __restrict__ si,
                                              const int* __restrict__ sj, const float* __restrict__ sw,
                                              const float* __restrict__ PT, float* __restrict__ La,
                                              const float* __restrict__ T, float* __restrict__ tr) {
  int p = blockIdx.x, bj = 0;
  while (p >= 8 - bj) { p -= 8 - bj; ++bj; }
  int bi = bj + p;
  int r0g = bi * 64, c0g = bj * 64;
  int m = min(*cnt, MAX_SE);
  int chunk = (m + NZ_SYRK - 1) / NZ_SYRK;
  int e0 = blockIdx.y * chunk;
  int e1 = min(m, e0 + chunk);

  __shared__ float As[16][68];
  __shared__ float Bs[16][68];
  int tid = threadIdx.x;
  int le = tid >> 4, f = tid & 15;
  int r0 = (tid >> 4) * 4, c0 = (tid & 15) * 4;
  float acc[4][4];
#pragma unroll
  for (int i = 0; i < 4; ++i)
#pragma unroll
    for (int j = 0; j < 4; ++j) acc[i][j] = 0.f;

  float w_ = 0.f;
  float4 ai = make_float4(0.f, 0.f, 0.f, 0.f), aj = ai, ci = ai, cj = ai;
  {
    int e = e0 + le;
    if (e < e1) {
      int i = si[e], j = sj[e];
      w_ = sw[e];
      const float* pi = &PT[(size_t)i * K_N];
      const float* pj = &PT[(size_t)j * K_N];
      ai = *(const float4*)(pi + r0g + f * 4);
      aj = *(const float4*)(pj + r0g + f * 4);
      if (bi != bj) {
        ci = *(const float4*)(pi + c0g + f * 4);
        cj = *(const float4*)(pj + c0g + f * 4);
      }
    }
  }

  for (int es = e0; es < e1; es += 16) {
    float sq = sqrtf(w_);
    float4 qa, qb;
    qa.x = sq * (ai.x - aj.x); qa.y = sq * (ai.y - aj.y);
    qa.z = sq * (ai.z - aj.z); qa.w = sq * (ai.w - aj.w);
    if (bi != bj) {
      qb.x = sq * (ci.x - cj.x); qb.y = sq * (ci.y - cj.y);
      qb.z = sq * (ci.z - cj.z); qb.w = sq * (ci.w - cj.w);
    } else {
      qb = qa;
    }
    __syncthreads();
    *(float4*)&As[le][f * 4] = qa;
    *(float4*)&Bs[le][f * 4] = qb;
    __syncthreads();

    {
      int e = es + 16 + le;
      w_ = 0.f;
      if (e < e1) {
        int i = si[e], j = sj[e];
        w_ = sw[e];
        const float* pi = &PT[(size_t)i * K_N];
        const float* pj = &PT[(size_t)j * K_N];
        ai = *(const float4*)(pi + r0g + f * 4);
        aj = *(const float4*)(pj + r0g + f * 4);
        if (bi != bj) {
          ci = *(const float4*)(pi + c0g + f * 4);
          cj = *(const float4*)(pj + c0g + f * 4);
        }
      }
    }

#pragma unroll
    for (int k = 0; k < 16; ++k) {
      float4 av = *(const float4*)&As[k][r0];
      float4 bv = *(const float4*)&Bs[k][c0];
      acc[0][0] += av.x * bv.x; acc[0][1] += av.x * bv.y; acc[0][2] += av.x * bv.z; acc[0][3] += av.x * bv.w;
      acc[1][0] += av.y * bv.x; acc[1][1] += av.y * bv.y; acc[1][2] += av.y * bv.z; acc[1][3] += av.y * bv.w;
      acc[2][0] += av.z * bv.x; acc[2][1] += av.z * bv.y; acc[2][2] += av.z * bv.z; acc[2][3] += av.z * bv.w;
      acc[3][0] += av.w * bv.x; acc[3][1] += av.w * bv.y; acc[3][2] += av.w * bv.z; acc[3][3] += av.w * bv.w;
    }
  }

  bool addeps = (blockIdx.y == 0) && (bi == bj);
  float tdot = 0.f;
#pragma unroll
  for (int i = 0; i < 4; ++i)
#pragma unroll
    for (int j = 0; j < 4; ++j) {
      float v = acc[i][j];
      int rg = r0g + r0 + i, cg = c0g + c0 + j;
      if (addeps && rg == cg) v += EPSL;
      atomicAdd(&La[(size_t)rg * K_N + cg], v);
      float sc = (bi != bj) ? 2.f : (rg == cg ? 1.f : (rg > cg ? 2.f : 0.f));
      if (sc != 0.f) tdot += sc * v * T[(size_t)rg * K_N + cg];
    }
  tdot += __shfl_down(tdot, 32); tdot += __shfl_down(tdot, 16); tdot += __shfl_down(tdot, 8);
  tdot += __shfl_down(tdot, 4);  tdot += __shfl_down(tdot, 2);  tdot += __shfl_down(tdot, 1);
  if ((tid & 63) == 0) atomicAdd(tr, tdot);
}

// ---------- batched-LDS 64x64 Cholesky core (one wave; lane = row). Column broadcast goes
// through smC with contiguous float4 reads (batched DS) instead of per-element shfl pairs.
// Valid for lower+diag inputs; upper-triangle junk never flows into lower/diag outputs. ----------
__device__ __forceinline__ float factor_core(float* __restrict__ a, float* __restrict__ smC, int lane) {
  float ls = 0.f;
#pragma unroll
  for (int c = 0; c < 64; ++c) {
    smC[lane] = a[c];                    // wave-wide write of (updated) column c
    float dc = smC[c];                   // broadcast read of diagonal (compiler inserts lgkmcnt)
    ls += logf(dc);
    float rdc = 1.0f / dc;
    float t = a[c] * rdc;                // l_r / sqrt(dc) * 1/sqrt(dc) combined
    a[c] *= rsqrtf(dc);                  // final L[r][c]
    int kk = c + 1;
#pragma unroll
    for (; kk < 64 && (kk & 3); ++kk) a[kk] -= t * smC[kk];
#pragma unroll
    for (; kk < 64; kk += 4) {
      float4 f = *(const float4*)&smC[kk];   // contiguous b128 reads, naturally batched
      a[kk + 0] -= t * f.x; a[kk + 1] -= t * f.y;
      a[kk + 2] -= t * f.z; a[kk + 3] -= t * f.w;
    }
  }
  return ls;
}

// ---------- k_cstep(s): one dispatch per panel step (s = 0..6).
// Each lower-tri pair (i,j >= s+1): build LT = L(s,s)^T in LDS (s==0: every block
// redundantly factors raw A(0,0) in-register; s>0: stage pre-factored tile),
// redundant in-block TRSM of C(i,s), C(j,s), then tile(i,j) -= P_i P_j^T.
// The i==j==s+1 block instead factors its updated diag tile -> global + ld entry.
// At s==6 the two (7,7) blocks elect a winner (device-scope atomic) that writes out[0].
__global__ __launch_bounds__(256, 1) void k_cstep(float* La, float* Lw1, float* __restrict__ ld,
                                                  const float* __restrict__ tr, float* __restrict__ out,
                                                  unsigned* __restrict__ donec, int s) {
  int m = blockIdx.y;
  float* A = m ? Lw1 : La;
  int tid = threadIdx.x;
  int nt2 = 7 - s;
  int q = blockIdx.x, lbj = 0;
  while (q >= nt2 - lbj) { q -= nt2 - lbj; ++lbj; }
  int lbi = lbj + q;
  int i = s + 1 + lbi, j = s + 1 + lbj;

  __shared__ float LT[64 * L68];       // LT[c][k] = L(s,s)[k][c]
  __shared__ float PiT[64 * L68];      // PiT[k][r] = P_i[r][k]
  __shared__ float PjT[64 * L68];      // P_j^T; reused as smF for the diag-factor block
  __shared__ float rinv[64];
  __shared__ float smC[64];

  if (s == 0) {
    // redundant in-register factor of raw A(0,0) by wave 0
    if (tid < 64) {
      float a[64];
#pragma unroll
      for (int qq = 0; qq < 16; ++qq) {
        float4 f = *(const float4*)&A[(size_t)tid * K_N + qq * 4];
        a[qq * 4 + 0] = f.x; a[qq * 4 + 1] = f.y; a[qq * 4 + 2] = f.z; a[qq * 4 + 3] = f.w;
      }
      float ls = factor_core(a, smC, tid);
      // lane k holds row k: LT[c][k] = L[k][c]  (entries with c>k are junk, never read)
#pragma unroll
      for (int c = 0; c < 64; ++c) LT[c * L68 + tid] = a[c];
      if (i == 1 && j == 1 && tid == 0) ld[m * 8] = ls;
    }
    __syncthreads();
  } else {
    for (int idx = tid; idx < 1024; idx += 256) {
      int r = idx >> 4, cq = (idx & 15) << 2;
      float4 f = *(const float4*)&A[(size_t)(s * 64 + r) * K_N + s * 64 + cq];
      LT[(cq + 0) * L68 + r] = f.x; LT[(cq + 1) * L68 + r] = f.y;
      LT[(cq + 2) * L68 + r] = f.z; LT[(cq + 3) * L68 + r] = f.w;
    }
    __syncthreads();
  }
  if (tid < 64) rinv[tid] = 1.0f / LT[tid * L68 + tid];
  __syncthreads();

  // TRSM: wave 0 -> rows of C(i,s); wave 1 -> rows of C(j,s) (skip if i==j).
  // Batched: per column, load the LT column slice into temp regs FIRST, then fma sweep.
  {
    int w = tid >> 6, r = tid & 63;
    bool act = (w == 0) || (w == 1 && i != j);
    if (act) {
      int rowblk = (w == 0) ? i : j;
      const float* src = &A[(size_t)(rowblk * 64 + r) * K_N + s * 64];
      float x[64];
#pragma unroll
      for (int qq = 0; qq < 16; ++qq) {
        float4 f = *(const float4*)(src + qq * 4);
        x[qq * 4 + 0] = f.x; x[qq * 4 + 1] = f.y; x[qq * 4 + 2] = f.z; x[qq * 4 + 3] = f.w;
      }
#pragma unroll
      for (int c = 0; c < 64; ++c) {
        float xc = x[c] * rinv[c];
        x[c] = xc;
        int kk = c + 1;
#pragma unroll
        for (; kk < 64 && (kk & 3); ++kk) x[kk] -= xc * LT[c * L68 + kk];
        const int nb = (64 - kk) >> 2;   // compile-time per unrolled c
        float4 tq[16];
#pragma unroll
        for (int b2 = 0; b2 < 16; ++b2)
          if (b2 < nb) tq[b2] = *(const float4*)&LT[c * L68 + kk + 4 * b2];
#pragma unroll
        for (int b2 = 0; b2 < 16; ++b2)
          if (b2 < nb) {
            x[kk + 4 * b2 + 0] -= xc * tq[b2].x; x[kk + 4 * b2 + 1] -= xc * tq[b2].y;
            x[kk + 4 * b2 + 2] -= xc * tq[b2].z; x[kk + 4 * b2 + 3] -= xc * tq[b2].w;
          }
      }
      float* dst = (w == 0) ? PiT : PjT;
#pragma unroll
      for (int k = 0; k < 64; ++k) dst[k * L68 + r] = x[k];
    }
  }
  __syncthreads();

  // GEMM: acc = P_i @ P_j^T  (P_j = P_i for diag pairs)
  const float* Bp = (i == j) ? PiT : PjT;
  int r0 = (tid >> 4) * 4, c0 = (tid & 15) * 4;
  float acc[4][4];
#pragma unroll
  for (int ii = 0; ii < 4; ++ii)
#pragma unroll
    for (int jj = 0; jj < 4; ++jj) acc[ii][jj] = 0.f;
#pragma unroll 8
  for (int k = 0; k < 64; ++k) {
    float4 av = *(const float4*)&PiT[k * L68 + r0];
    float4 bv = *(const float4*)&Bp[k * L68 + c0];
    acc[0][0] += av.x * bv.x; acc[0][1] += av.x * bv.y; acc[0][2] += av.x * bv.z; acc[0][3] += av.x * bv.w;
    acc[1][0] += av.y * bv.x; acc[1][1] += av.y * bv.y; acc[1][2] += av.y * bv.z; acc[1][3] += av.y * bv.w;
    acc[2][0] += av.z * bv.x; acc[2][1] += av.z * bv.y; acc[2][2] += av.z * bv.z; acc[2][3] += av.z * bv.w;
    acc[3][0] += av.w * bv.x; acc[3][1] += av.w * bv.y; acc[3][2] += av.w * bv.z; acc[3][3] += av.w * bv.w;
  }

  if (i != j || i > s + 1) {
    // trailing update: tile(i,j) -= acc  (includes diag tiles i==j>s+1 — NOT factored yet)
#pragma unroll
    for (int ii = 0; ii < 4; ++ii) {
      float* cp = &A[(size_t)(i * 64 + r0 + ii) * K_N + j * 64 + c0];
      float4 o = *(const float4*)cp;
      float4 wv;
      wv.x = o.x - acc[ii][0]; wv.y = o.y - acc[ii][1];
      wv.z = o.z - acc[ii][2]; wv.w = o.w - acc[ii][3];
      *(float4*)cp = wv;
    }
  } else {
    // next-panel diag block (i == j == s+1): updated tile -> smF (reuse PjT), factor
#pragma unroll
    for (int ii = 0; ii < 4; ++ii) {
      const float* cp = &A[(size_t)(i * 64 + r0 + ii) * K_N + i * 64 + c0];
      float4 o = *(const float4*)cp;
      PjT[(r0 + ii) * L68 + c0 + 0] = o.x - acc[ii][0];
      PjT[(r0 + ii) * L68 + c0 + 1] = o.y - acc[ii][1];
      PjT[(r0 + ii) * L68 + c0 + 2] = o.z - acc[ii][2];
      PjT[(r0 + ii) * L68 + c0 + 3] = o.w - acc[ii][3];
    }
    __syncthreads();
    if (tid < 64) {
      float a[64];
#pragma unroll
      for (int qq = 0; qq < 16; ++qq) {
        float4 f = *(const float4*)&PjT[tid * L68 + qq * 4];
        a[qq * 4 + 0] = f.x; a[qq * 4 + 1] = f.y; a[qq * 4 + 2] = f.z; a[qq * 4 + 3] = f.w;
      }
      float ls = factor_core(a, smC, tid);
#pragma unroll
      for (int qq = 0; qq < 16; ++qq) {
        float4 f;
        f.x = a[qq * 4 + 0]; f.y = a[qq * 4 + 1]; f.z = a[qq * 4 + 2]; f.w = a[qq * 4 + 3];
        *(float4*)&A[(size_t)(i * 64 + tid) * K_N + i * 64 + qq * 4] = f;
      }
      if (tid == 0) ld[m * 8 + s + 1] = ls;
    }

    if (s == 6 && tid == 0) {
      // final step: elect the last of the two (7,7) blocks to assemble the output
      __threadfence();
      unsigned old = __hip_atomic_fetch_add(donec, 1u, __ATOMIC_ACQ_REL, __HIP_MEMORY_SCOPE_AGENT);
      if (old == 1u) {
        float lsum = 0.f;
#pragma unroll
        for (int t = 0; t < 16; ++t)
          lsum += __hip_atomic_load(&ld[t], __ATOMIC_ACQUIRE, __HIP_MEMORY_SCOPE_AGENT);
        float trv = __hip_atomic_load(tr, __ATOMIC_ACQUIRE, __HIP_MEMORY_SCOPE_AGENT);
        out[0] = -lsum - (float)K_N + trv;
      }
    }
  }
}

extern "C" void kernel_launch(void* const* d_in, const int* in_sizes, int n_in,
                              void* d_out, int out_size, void* d_ws, size_t ws_size,
                              hipStream_t stream) {
  const float* X  = (const float*)d_in[0];   // inputs  [V,128]
  const float* T  = (const float*)d_in[1];   // targets [K,K]
  const int*   ei = (const int*)d_in[2];     // edge_index [2,E]
  const float* P  = (const float*)d_in[3];   // pmat [K,V]
  float* out = (float*)d_out;
  char* ws = (char*)d_ws;

  // workspace layout (bytes); [0, 1314816) is one contiguous zero-memset region
  int*      cnt    = (int*)(ws + 0);
  float*    tr     = (float*)(ws + 16);
  float*    ld     = (float*)(ws + 32);           // 16 floats
  unsigned* donec  = (unsigned*)(ws + 192);       // output-election counter
  unsigned* htab   = (unsigned*)(ws + 4096);      // 65536 u32 (256 KB) -> 266240
  float*    La     = (float*)(ws + 266240);       // K*K (1 MB) -> 1314816 (zeroed; lower filled)
  float*    Lw1    = (float*)(ws + 1314816);      // K*K (1 MB) -> 2363392 (copied from T in k_pre)
  int*      si     = (int*)(ws + 2363392);        // 16384 ints -> 2428928
  int*      sj     = (int*)(ws + 2428928);        // 16384 ints -> 2494464
  float*    sw     = (float*)(ws + 2494464);      // 16384 floats -> 2560000
  float*    PT     = (float*)(ws + 2560000);      // V*K floats (16 MB) -> 19337216

  hipMemsetAsync(ws, 0, 1314816, stream);         // cnt, tr, ld, donec, htab, La

  k_pre<<<NB_TR + NB_CP + NB_ED, 256, 0, stream>>>(P, PT, X, ei, cnt, si, sj, sw, htab, T, Lw1);
  k_syrk<<<dim3(36, NZ_SYRK), 256, 0, stream>>>(cnt, si, sj, sw, PT, La, T, tr);

  for (int s = 0; s < 7; ++s) {
    int nt2 = 7 - s;
    k_cstep<<<dim3(nt2 * (nt2 + 1) / 2, 2), 256, 0, stream>>>(La, Lw1, ld, tr, out, donec, s);
  }
}

// Round 14
// 784.875 us; speedup vs baseline: 1.4758x; 1.4758x over previous
//
#include <hip/hip_runtime.h>
#include <math.h>

#define V_N 8192
#define D_F 128
#define E_N 262144
#define K_N 512
#define DMAXF 0.5f
#define EPSW 1e-8f
#define EPSL 1e-5f
#define MAX_SE 16384
#define NZ_SYRK 24
#define L68 68

#define NB_TR 1024
#define NB_CP 256
#define NB_ED (E_N / 32)

// ---------- fused pre-pass: transpose pmat (KxV)->PT (VxK) | Lw1 <- T | edge dedup ----------
__global__ __launch_bounds__(256) void k_pre(const float* __restrict__ P, float* __restrict__ PT,
                                             const float* __restrict__ X, const int* __restrict__ ei,
                                             int* __restrict__ cnt, int* __restrict__ si,
                                             int* __restrict__ sj, float* __restrict__ sw,
                                             unsigned* __restrict__ htab,
                                             const float* __restrict__ T, float* __restrict__ Lw1) {
  int b = blockIdx.x, tid = threadIdx.x;
  if (b < NB_TR) {
    __shared__ float tl[64][65];
    int v0 = (b & 127) * 64, k0 = (b >> 7) * 64;
    int c4 = tid & 15, rq = tid >> 4;
#pragma unroll
    for (int rr = 0; rr < 4; ++rr) {
      int r = rq + 16 * rr;
      float4 f = *(const float4*)&P[(size_t)(k0 + r) * V_N + v0 + c4 * 4];
      tl[r][c4 * 4 + 0] = f.x; tl[r][c4 * 4 + 1] = f.y;
      tl[r][c4 * 4 + 2] = f.z; tl[r][c4 * 4 + 3] = f.w;
    }
    __syncthreads();
#pragma unroll
    for (int rr = 0; rr < 4; ++rr) {
      int r = rq + 16 * rr;   // v-local row
      float4 f;
      f.x = tl[c4 * 4 + 0][r]; f.y = tl[c4 * 4 + 1][r];
      f.z = tl[c4 * 4 + 2][r]; f.w = tl[c4 * 4 + 3][r];
      *(float4*)&PT[(size_t)(v0 + r) * K_N + k0 + c4 * 4] = f;
    }
  } else if (b < NB_TR + NB_CP) {
    int idx = (b - NB_TR) * 256 + tid;
    ((float4*)Lw1)[idx] = ((const float4*)T)[idx];
  } else {
    // per-edge distance (8 lanes/edge), strong-edge dedup + compaction
    int t = (b - NB_TR - NB_CP) * 256 + tid;
    int e = t >> 3, lane = t & 7;
    int i = ei[e], j = ei[E_N + e];
    const float4* xi = (const float4*)(X + (size_t)i * D_F);
    const float4* xj = (const float4*)(X + (size_t)j * D_F);
    float4 A0 = xi[lane * 4 + 0], A1 = xi[lane * 4 + 1], A2 = xi[lane * 4 + 2], A3 = xi[lane * 4 + 3];
    float4 B0 = xj[lane * 4 + 0], B1 = xj[lane * 4 + 1], B2 = xj[lane * 4 + 2], B3 = xj[lane * 4 + 3];
    // force all 8 b128 gathers live simultaneously (8-deep MLP; compiler alone picks VGPR=16
    // and serializes to ~4 in flight — measured R5)
    asm volatile("" :: "v"(A0.x), "v"(A1.x), "v"(A2.x), "v"(A3.x),
                       "v"(B0.x), "v"(B1.x), "v"(B2.x), "v"(B3.x));
    float d = 0.f, dx;
    dx = A0.x - B0.x; d += dx * dx; dx = A0.y - B0.y; d += dx * dx;
    dx = A0.z - B0.z; d += dx * dx; dx = A0.w - B0.w; d += dx * dx;
    dx = A1.x - B1.x; d += dx * dx; dx = A1.y - B1.y; d += dx * dx;
    dx = A1.z - B1.z; d += dx * dx; dx = A1.w - B1.w; d += dx * dx;
    dx = A2.x - B2.x; d += dx * dx; dx = A2.y - B2.y; d += dx * dx;
    dx = A2.z - B2.z; d += dx * dx; dx = A2.w - B2.w; d += dx * dx;
    dx = A3.x - B3.x; d += dx * dx; dx = A3.y - B3.y; d += dx * dx;
    dx = A3.z - B3.z; d += dx * dx; dx = A3.w - B3.w; d += dx * dx;
    d += __shfl_xor(d, 1);
    d += __shfl_xor(d, 2);
    d += __shfl_xor(d, 4);
    if (lane == 0 && d <= DMAXF) {
      float w = expf(-d);
      unsigned a = (unsigned)min(i, j), bb = (unsigned)max(i, j);
      unsigned key = a * 8192u + bb;         // key==0 impossible (a<b)
      unsigned h = (key * 2654435761u) >> 16;
      bool isnew = false;
      for (int probe = 0; probe < 65536; ++probe) {
        unsigned slot = (h + (unsigned)probe) & 65535u;
        unsigned prev = atomicCAS(&htab[slot], 0u, key);
        if (prev == 0u) { isnew = true; break; }
        if (prev == key) break;              // duplicate pair -> reference counts it once
      }
      if (isnew) {
        int p = atomicAdd(cnt, 1);
        if (p < MAX_SE) { si[p] = i; sj[p] = j; sw[p] = w; }
      }
    }
  }
}

// ---------- La(lower) += Q^T Q + eps*I, Q rows = sqrt(w)*(PT[i]-PT[j]); fused trace epilogue ----------
__global__ __launch_bounds__(256) void k_syrk(const int* __restrict__ cnt, const int* __restrict__ si,
                                              const int* __restrict__ sj, const float* __restrict__ sw,
                                              const float* __restrict__ PT, float* __restrict__ La,
                                              const float* __restrict__ T, float* __restrict__ tr) {
  int p = blockIdx.x, bj = 0;
  while (p >= 8 - bj) { p -= 8 - bj; ++bj; }
  int bi = bj + p;
  int r0g = bi * 64, c0g = bj * 64;
  int m = min(*cnt, MAX_SE);
  int chunk = (m + NZ_SYRK - 1) / NZ_SYRK;
  int e0 = blockIdx.y * chunk;
  int e1 = min(m, e0 + chunk);

  __shared__ float As[16][68];
  __shared__ float Bs[16][68];
  int tid = threadIdx.x;
  int le = tid >> 4, f = tid & 15;
  int r0 = (tid >> 4) * 4, c0 = (tid & 15) * 4;
  float acc[4][4];
#pragma unroll
  for (int i = 0; i < 4; ++i)
#pragma unroll
    for (int j = 0; j < 4; ++j) acc[i][j] = 0.f;

  float w_ = 0.f;
  float4 ai = make_float4(0.f, 0.f, 0.f, 0.f), aj = ai, ci = ai, cj = ai;
  {
    int e = e0 + le;
    if (e < e1) {
      int i = si[e], j = sj[e];
      w_ = sw[e];
      const float* pi = &PT[(size_t)i * K_N];
      const float* pj = &PT[(size_t)j * K_N];
      ai = *(const float4*)(pi + r0g + f * 4);
      aj = *(const float4*)(pj + r0g + f * 4);
      if (bi != bj) {
        ci = *(const float4*)(pi + c0g + f * 4);
        cj = *(const float4*)(pj + c0g + f * 4);
      }
    }
  }

  for (int es = e0; es < e1; es += 16) {
    float sq = sqrtf(w_);
    float4 qa, qb;
    qa.x = sq * (ai.x - aj.x); qa.y = sq * (ai.y - aj.y);
    qa.z = sq * (ai.z - aj.z); qa.w = sq * (ai.w - aj.w);
    if (bi != bj) {
      qb.x = sq * (ci.x - cj.x); qb.y = sq * (ci.y - cj.y);
      qb.z = sq * (ci.z - cj.z); qb.w = sq * (ci.w - cj.w);
    } else {
      qb = qa;
    }
    __syncthreads();
    *(float4*)&As[le][f * 4] = qa;
    *(float4*)&Bs[le][f * 4] = qb;
    __syncthreads();

    {
      int e = es + 16 + le;
      w_ = 0.f;
      if (e < e1) {
        int i = si[e], j = sj[e];
        w_ = sw[e];
        const float* pi = &PT[(size_t)i * K_N];
        const float* pj = &PT[(size_t)j * K_N];
        ai = *(const float4*)(pi + r0g + f * 4);
        aj = *(const float4*)(pj + r0g + f * 4);
        if (bi != bj) {
          ci = *(const float4*)(pi + c0g + f * 4);
          cj = *(const float4*)(pj + c0g + f * 4);
        }
      }
    }

#pragma unroll
    for (int k = 0; k < 16; ++k) {
      float4 av = *(const float4*)&As[k][r0];
      float4 bv = *(const float4*)&Bs[k][c0];
      acc[0][0] += av.x * bv.x; acc[0][1] += av.x * bv.y; acc[0][2] += av.x * bv.z; acc[0][3] += av.x * bv.w;
      acc[1][0] += av.y * bv.x; acc[1][1] += av.y * bv.y; acc[1][2] += av.y * bv.z; acc[1][3] += av.y * bv.w;
      acc[2][0] += av.z * bv.x; acc[2][1] += av.z * bv.y; acc[2][2] += av.z * bv.z; acc[2][3] += av.z * bv.w;
      acc[3][0] += av.w * bv.x; acc[3][1] += av.w * bv.y; acc[3][2] += av.w * bv.z; acc[3][3] += av.w * bv.w;
    }
  }

  bool addeps = (blockIdx.y == 0) && (bi == bj);
  float tdot = 0.f;
#pragma unroll
  for (int i = 0; i < 4; ++i)
#pragma unroll
    for (int j = 0; j < 4; ++j) {
      float v = acc[i][j];
      int rg = r0g + r0 + i, cg = c0g + c0 + j;
      if (addeps && rg == cg) v += EPSL;
      atomicAdd(&La[(size_t)rg * K_N + cg], v);
      float sc = (bi != bj) ? 2.f : (rg == cg ? 1.f : (rg > cg ? 2.f : 0.f));
      if (sc != 0.f) tdot += sc * v * T[(size_t)rg * K_N + cg];
    }
  tdot += __shfl_down(tdot, 32); tdot += __shfl_down(tdot, 16); tdot += __shfl_down(tdot, 8);
  tdot += __shfl_down(tdot, 4);  tdot += __shfl_down(tdot, 2);  tdot += __shfl_down(tdot, 1);
  if ((tid & 63) == 0) atomicAdd(tr, tdot);
}

// ---------- shfl-based in-register 64x64 Cholesky recurrence (lane = row) ----------
__device__ __forceinline__ float factor64_shfl(float a[64]) {
  float ls = 0.f;
#pragma unroll
  for (int c = 0; c < 64; ++c) {
    float dc = __shfl(a[c], c);          // fully-updated diagonal = L_cc^2
    ls += logf(dc);
    float rs = rsqrtf(dc);
    a[c] *= rs;
#pragma unroll
    for (int k = c + 1; k < 64; ++k)
      a[k] -= a[c] * __shfl(a[c], k);
  }
  return ls;
}

// ---------- in-register 64x64 Cholesky by one wave from LDS tile; writes rows to global ----------
__device__ __forceinline__ void factor64_lds(const float* __restrict__ smF, float* A, int j0,
                                             float* __restrict__ ldout, int lane) {
  float a[64];
#pragma unroll
  for (int qq = 0; qq < 16; ++qq) {
    float4 f = *(const float4*)&smF[lane * L68 + qq * 4];
    a[qq * 4 + 0] = f.x; a[qq * 4 + 1] = f.y; a[qq * 4 + 2] = f.z; a[qq * 4 + 3] = f.w;
  }
  float ls = factor64_shfl(a);
#pragma unroll
  for (int qq = 0; qq < 16; ++qq) {
    float4 f;
    f.x = a[qq * 4 + 0]; f.y = a[qq * 4 + 1]; f.z = a[qq * 4 + 2]; f.w = a[qq * 4 + 3];
    *(float4*)&A[(size_t)(j0 + lane) * K_N + j0 + qq * 4] = f;
  }
  if (lane == 0) *ldout = ls;
}

// ---------- k_fact0: factor tile (0,0) of both matrices (1 wave each) ----------
__global__ __launch_bounds__(64) void k_fact0(float* La, float* Lw1, float* __restrict__ ld) {
  int m = blockIdx.x;
  float* A = m ? Lw1 : La;
  int lane = threadIdx.x;
  float a[64];
#pragma unroll
  for (int qq = 0; qq < 16; ++qq) {
    float4 f = *(const float4*)&A[(size_t)lane * K_N + qq * 4];
    a[qq * 4 + 0] = f.x; a[qq * 4 + 1] = f.y; a[qq * 4 + 2] = f.z; a[qq * 4 + 3] = f.w;
  }
  float ls = factor64_shfl(a);
#pragma unroll
  for (int qq = 0; qq < 16; ++qq) {
    float4 f;
    f.x = a[qq * 4 + 0]; f.y = a[qq * 4 + 1]; f.z = a[qq * 4 + 2]; f.w = a[qq * 4 + 3];
    *(float4*)&A[(size_t)lane * K_N + qq * 4] = f;
  }
  if (lane == 0) ld[m * 8] = ls;
}

// ---------- k_cstep(s), s = 0..4: R10-verbatim panel step ----------
__global__ __launch_bounds__(256, 1) void k_cstep(float* La, float* Lw1, float* __restrict__ ld, int s) {
  int m = blockIdx.y;
  float* A = m ? Lw1 : La;
  int tid = threadIdx.x;
  int nt2 = 7 - s;
  int q = blockIdx.x, lbj = 0;
  while (q >= nt2 - lbj) { q -= nt2 - lbj; ++lbj; }
  int lbi = lbj + q;
  int i = s + 1 + lbi, j = s + 1 + lbj;

  __shared__ float LT[64 * L68];       // LT[c][k] = L(s,s)[k][c]; reused as smF
  __shared__ float PiT[64 * L68];      // PiT[k][r] = P_i[r][k]
  __shared__ float PjT[64 * L68];
  __shared__ float rinv[64];

  // stage L(s,s) transposed
  for (int idx = tid; idx < 1024; idx += 256) {
    int r = idx >> 4, cq = (idx & 15) << 2;
    float4 f = *(const float4*)&A[(size_t)(s * 64 + r) * K_N + s * 64 + cq];
    LT[(cq + 0) * L68 + r] = f.x; LT[(cq + 1) * L68 + r] = f.y;
    LT[(cq + 2) * L68 + r] = f.z; LT[(cq + 3) * L68 + r] = f.w;
  }
  __syncthreads();
  if (tid < 64) rinv[tid] = 1.0f / LT[tid * L68 + tid];
  __syncthreads();

  // TRSM: wave 0 -> rows of C(i,s); wave 1 -> rows of C(j,s) (skip if i==j)
  {
    int w = tid >> 6, r = tid & 63;
    bool act = (w == 0) || (w == 1 && i != j);
    if (act) {
      int rowblk = (w == 0) ? i : j;
      const float* src = &A[(size_t)(rowblk * 64 + r) * K_N + s * 64];
      float x[64];
#pragma unroll
      for (int qq = 0; qq < 16; ++qq) {
        float4 f = *(const float4*)(src + qq * 4);
        x[qq * 4 + 0] = f.x; x[qq * 4 + 1] = f.y; x[qq * 4 + 2] = f.z; x[qq * 4 + 3] = f.w;
      }
#pragma unroll
      for (int c = 0; c < 64; ++c) {
        float xc = x[c] * rinv[c];
        x[c] = xc;
        int kk = c + 1;
#pragma unroll
        for (; kk < 64 && (kk & 3); ++kk) x[kk] -= xc * LT[c * L68 + kk];
#pragma unroll
        for (; kk < 64; kk += 4) {
          float4 f = *(const float4*)&LT[c * L68 + kk];
          x[kk + 0] -= xc * f.x; x[kk + 1] -= xc * f.y;
          x[kk + 2] -= xc * f.z; x[kk + 3] -= xc * f.w;
        }
      }
      float* dst = (w == 0) ? PiT : PjT;
#pragma unroll
      for (int k = 0; k < 64; ++k) dst[k * L68 + r] = x[k];
    }
  }
  __syncthreads();

  // GEMM: acc = P_i @ P_j^T  (P_j = P_i for diag pairs)
  const float* Bp = (i == j) ? PiT : PjT;
  int r0 = (tid >> 4) * 4, c0 = (tid & 15) * 4;
  float acc[4][4];
#pragma unroll
  for (int ii = 0; ii < 4; ++ii)
#pragma unroll
    for (int jj = 0; jj < 4; ++jj) acc[ii][jj] = 0.f;
#pragma unroll 8
  for (int k = 0; k < 64; ++k) {
    float4 av = *(const float4*)&PiT[k * L68 + r0];
    float4 bv = *(const float4*)&Bp[k * L68 + c0];
    acc[0][0] += av.x * bv.x; acc[0][1] += av.x * bv.y; acc[0][2] += av.x * bv.z; acc[0][3] += av.x * bv.w;
    acc[1][0] += av.y * bv.x; acc[1][1] += av.y * bv.y; acc[1][2] += av.y * bv.z; acc[1][3] += av.y * bv.w;
    acc[2][0] += av.z * bv.x; acc[2][1] += av.z * bv.y; acc[2][2] += av.z * bv.z; acc[2][3] += av.z * bv.w;
    acc[3][0] += av.w * bv.x; acc[3][1] += av.w * bv.y; acc[3][2] += av.w * bv.z; acc[3][3] += av.w * bv.w;
  }

  if (i != j || i > s + 1) {
    // trailing update: tile(i,j) -= acc  (includes diag tiles i==j>s+1 — NOT factored yet)
#pragma unroll
    for (int ii = 0; ii < 4; ++ii) {
      float* cp = &A[(size_t)(i * 64 + r0 + ii) * K_N + j * 64 + c0];
      float4 o = *(const float4*)cp;
      float4 wv;
      wv.x = o.x - acc[ii][0]; wv.y = o.y - acc[ii][1];
      wv.z = o.z - acc[ii][2]; wv.w = o.w - acc[ii][3];
      *(float4*)cp = wv;
    }
  } else {
    // next-panel diag block (i == j == s+1): updated tile -> smF (reuse PjT), factor
#pragma unroll
    for (int ii = 0; ii < 4; ++ii) {
      const float* cp = &A[(size_t)(i * 64 + r0 + ii) * K_N + i * 64 + c0];
      float4 o = *(const float4*)cp;
      PjT[(r0 + ii) * L68 + c0 + 0] = o.x - acc[ii][0];
      PjT[(r0 + ii) * L68 + c0 + 1] = o.y - acc[ii][1];
      PjT[(r0 + ii) * L68 + c0 + 2] = o.z - acc[ii][2];
      PjT[(r0 + ii) * L68 + c0 + 3] = o.w - acc[ii][3];
    }
    __syncthreads();
    if (tid < 64)
      factor64_lds(PjT, A, i * 64, &ld[m * 8 + s + 1], tid);
  }
}

// ---------- small LDS tile update: U -= Pi @ Pj^T (all in LDS, 256 threads) ----------
__device__ __forceinline__ void upd_tile_lds(float* __restrict__ U, const float* __restrict__ Pi,
                                             const float* __restrict__ Pj, int tid) {
  int r0 = (tid >> 4) * 4, c0 = (tid & 15) * 4;
  float acc[4][4];
#pragma unroll
  for (int ii = 0; ii < 4; ++ii)
#pragma unroll
    for (int jj = 0; jj < 4; ++jj) acc[ii][jj] = 0.f;
#pragma unroll 8
  for (int k = 0; k < 64; ++k) {
    float4 av = *(const float4*)&Pi[k * L68 + r0];
    float4 bv = *(const float4*)&Pj[k * L68 + c0];
    acc[0][0] += av.x * bv.x; acc[0][1] += av.x * bv.y; acc[0][2] += av.x * bv.z; acc[0][3] += av.x * bv.w;
    acc[1][0] += av.y * bv.x; acc[1][1] += av.y * bv.y; acc[1][2] += av.y * bv.z; acc[1][3] += av.y * bv.w;
    acc[2][0] += av.z * bv.x; acc[2][1] += av.z * bv.y; acc[2][2] += av.z * bv.z; acc[2][3] += av.z * bv.w;
    acc[3][0] += av.w * bv.x; acc[3][1] += av.w * bv.y; acc[3][2] += av.w * bv.z; acc[3][3] += av.w * bv.w;
  }
#pragma unroll
  for (int ii = 0; ii < 4; ++ii)
#pragma unroll
    for (int jj = 0; jj < 4; ++jj)
      U[(r0 + ii) * L68 + c0 + jj] -= acc[ii][jj];
}

// ---------- k_tail: merged steps s=5,6 + final factor + output assembly (1 block per matrix).
// Everything in LDS; NO global writes except ld. L panels/diag tiles of steps 5-7 are
// never consumed downstream, so nothing is written back. ----------
__global__ __launch_bounds__(256, 1) void k_tail(float* La, float* Lw1, float* __restrict__ ld,
                                                 const float* __restrict__ tr, float* __restrict__ out,
                                                 unsigned* __restrict__ donec) {
  int m = blockIdx.x;
  float* A = m ? Lw1 : La;
  int tid = threadIdx.x;
  __shared__ float LT[64 * L68];
  __shared__ float P6s[64 * L68];
  __shared__ float P7s[64 * L68];
  __shared__ float U66[64 * L68];
  __shared__ float U76[64 * L68];
  __shared__ float U77[64 * L68];
  __shared__ float rinv[64];

  // stage L(5,5)^T + trailing tiles (6,6),(7,6),(7,7) (updated through column 4)
  for (int idx = tid; idx < 1024; idx += 256) {
    int r = idx >> 4, cq = (idx & 15) << 2;
    float4 f = *(const float4*)&A[(size_t)(320 + r) * K_N + 320 + cq];
    LT[(cq + 0) * L68 + r] = f.x; LT[(cq + 1) * L68 + r] = f.y;
    LT[(cq + 2) * L68 + r] = f.z; LT[(cq + 3) * L68 + r] = f.w;
    *(float4*)&U66[r * L68 + cq] = *(const float4*)&A[(size_t)(384 + r) * K_N + 384 + cq];
    *(float4*)&U76[r * L68 + cq] = *(const float4*)&A[(size_t)(448 + r) * K_N + 384 + cq];
    *(float4*)&U77[r * L68 + cq] = *(const float4*)&A[(size_t)(448 + r) * K_N + 448 + cq];
  }
  __syncthreads();
  if (tid < 64) rinv[tid] = 1.0f / LT[tid * L68 + tid];
  __syncthreads();

  // step-5 TRSM: wave 0 -> rows of C(6,5); wave 1 -> rows of C(7,5)
  {
    int w = tid >> 6, r = tid & 63;
    if (w < 2) {
      const float* src = &A[(size_t)((w ? 448 : 384) + r) * K_N + 320];
      float x[64];
#pragma unroll
      for (int qq = 0; qq < 16; ++qq) {
        float4 f = *(const float4*)(src + qq * 4);
        x[qq * 4 + 0] = f.x; x[qq * 4 + 1] = f.y; x[qq * 4 + 2] = f.z; x[qq * 4 + 3] = f.w;
      }
#pragma unroll
      for (int c = 0; c < 64; ++c) {
        float xc = x[c] * rinv[c];
        x[c] = xc;
        int kk = c + 1;
#pragma unroll
        for (; kk < 64 && (kk & 3); ++kk) x[kk] -= xc * LT[c * L68 + kk];
#pragma unroll
        for (; kk < 64; kk += 4) {
          float4 f = *(const float4*)&LT[c * L68 + kk];
          x[kk + 0] -= xc * f.x; x[kk + 1] -= xc * f.y;
          x[kk + 2] -= xc * f.z; x[kk + 3] -= xc * f.w;
        }
      }
      float* dst = w ? P7s : P6s;
#pragma unroll
      for (int k = 0; k < 64; ++k) dst[k * L68 + r] = x[k];
    }
  }
  __syncthreads();

  // step-5 trailing updates (all in LDS)
  upd_tile_lds(U66, P6s, P6s, tid);
  upd_tile_lds(U76, P7s, P6s, tid);
  upd_tile_lds(U77, P7s, P7s, tid);
  __syncthreads();

  // factor (6,6) -> LT (transposed, overwrites dead L(5,5)^T), logdet part 6
  if (tid < 64) {
    float a[64];
#pragma unroll
    for (int qq = 0; qq < 16; ++qq) {
      float4 f = *(const float4*)&U66[tid * L68 + qq * 4];
      a[qq * 4 + 0] = f.x; a[qq * 4 + 1] = f.y; a[qq * 4 + 2] = f.z; a[qq * 4 + 3] = f.w;
    }
    float ls = factor64_shfl(a);
#pragma unroll
    for (int c = 0; c < 64; ++c) LT[c * L68 + tid] = a[c];
    if (tid == 0) ld[m * 8 + 6] = ls;
    rinv[tid] = 1.0f / LT[tid * L68 + tid];
  }
  // step-6 TRSM (wave 0 only): rows of U76 vs L(6,6) -> reuse P6s
  if (tid < 64) {
    float x[64];
#pragma unroll
    for (int qq = 0; qq < 16; ++qq) {
      float4 f = *(const float4*)&U76[tid * L68 + qq * 4];
      x[qq * 4 + 0] = f.x; x[qq * 4 + 1] = f.y; x[qq * 4 + 2] = f.z; x[qq * 4 + 3] = f.w;
    }
#pragma unroll
    for (int c = 0; c < 64; ++c) {
      float xc = x[c] * rinv[c];
      x[c] = xc;
      int kk = c + 1;
#pragma unroll
      for (; kk < 64 && (kk & 3); ++kk) x[kk] -= xc * LT[c * L68 + kk];
#pragma unroll
      for (; kk < 64; kk += 4) {
        float4 f = *(const float4*)&LT[c * L68 + kk];
        x[kk + 0] -= xc * f.x; x[kk + 1] -= xc * f.y;
        x[kk + 2] -= xc * f.z; x[kk + 3] -= xc * f.w;
      }
    }
#pragma unroll
    for (int k = 0; k < 64; ++k) P6s[k * L68 + tid] = x[k];
  }
  __syncthreads();

  // step-6 trailing update of (7,7)
  upd_tile_lds(U77, P6s, P6s, tid);
  __syncthreads();

  // factor (7,7), logdet part 7, then output election
  if (tid < 64) {
    float a[64];
#pragma unroll
    for (int qq = 0; qq < 16; ++qq) {
      float4 f = *(const float4*)&U77[tid * L68 + qq * 4];
      a[qq * 4 + 0] = f.x; a[qq * 4 + 1] = f.y; a[qq * 4 + 2] = f.z; a[qq * 4 + 3] = f.w;
    }
    float ls = factor64_shfl(a);
    if (tid == 0) {
      ld[m * 8 + 7] = ls;
      __threadfence();
      unsigned old = __hip_atomic_fetch_add(donec, 1u, __ATOMIC_ACQ_REL, __HIP_MEMORY_SCOPE_AGENT);
      if (old == 1u) {
        float lsum = 0.f;
#pragma unroll
        for (int t = 0; t < 16; ++t)
          lsum += __hip_atomic_load(&ld[t], __ATOMIC_ACQUIRE, __HIP_MEMORY_SCOPE_AGENT);
        float trv = __hip_atomic_load(tr, __ATOMIC_ACQUIRE, __HIP_MEMORY_SCOPE_AGENT);
        out[0] = -lsum - (float)K_N + trv;
      }
    }
  }
}

extern "C" void kernel_launch(void* const* d_in, const int* in_sizes, int n_in,
                              void* d_out, int out_size, void* d_ws, size_t ws_size,
                              hipStream_t stream) {
  const float* X  = (const float*)d_in[0];   // inputs  [V,128]
  const float* T  = (const float*)d_in[1];   // targets [K,K]
  const int*   ei = (const int*)d_in[2];     // edge_index [2,E]
  const float* P  = (const float*)d_in[3];   // pmat [K,V]
  float* out = (float*)d_out;
  char* ws = (char*)d_ws;

  // workspace layout (bytes); [0, 1314816) is one contiguous zero-memset region
  int*      cnt    = (int*)(ws + 0);
  float*    tr     = (float*)(ws + 16);
  float*    ld     = (float*)(ws + 32);           // 16 floats
  unsigned* donec  = (unsigned*)(ws + 192);       // output-election counter
  unsigned* htab   = (unsigned*)(ws + 4096);      // 65536 u32 (256 KB) -> 266240
  float*    La     = (float*)(ws + 266240);       // K*K (1 MB) -> 1314816 (zeroed; lower filled)
  float*    Lw1    = (float*)(ws + 1314816);      // K*K (1 MB) -> 2363392 (copied from T in k_pre)
  int*      si     = (int*)(ws + 2363392);        // 16384 ints -> 2428928
  int*      sj     = (int*)(ws + 2428928);        // 16384 ints -> 2494464
  float*    sw     = (float*)(ws + 2494464);      // 16384 floats -> 2560000
  float*    PT     = (float*)(ws + 2560000);      // V*K floats (16 MB) -> 19337216

  hipMemsetAsync(ws, 0, 1314816, stream);         // cnt, tr, ld, donec, htab, La

  k_pre<<<NB_TR + NB_CP + NB_ED, 256, 0, stream>>>(P, PT, X, ei, cnt, si, sj, sw, htab, T, Lw1);
  k_syrk<<<dim3(36, NZ_SYRK), 256, 0, stream>>>(cnt, si, sj, sw, PT, La, T, tr);

  k_fact0<<<2, 64, 0, stream>>>(La, Lw1, ld);
  for (int s = 0; s < 5; ++s) {
    int nt2 = 7 - s;
    k_cstep<<<dim3(nt2 * (nt2 + 1) / 2, 2), 256, 0, stream>>>(La, Lw1, ld, s);
  }
  k_tail<<<2, 256, 0, stream>>>(La, Lw1, ld, tr, out, donec);
}